// Round 6
// baseline (164.303 us; speedup 1.0000x reference)
//
#include <hip/hip_runtime.h>
#include <hip/hip_bf16.h>
#include <math.h>

// ComplexProjection: out[b,r,p] = | sum_s complex(xr,xi)[b,r,s] * w[r,s,p] |
// B=32768, R=16, S=128, P=128. Combined-traffic floor ~774MB / 6.3TB/s ~= 123us.
// R6: T4 counted-vmcnt pipeline (never drain to 0 in the loop):
//   - 3-buffer LDS ring (48KB), stages s+1,s+2 in flight while computing s.
//   - per-iter: s_waitcnt vmcnt(N) (counted, literal) -> raw s_barrier ->
//     sched_barrier(0) -> STAGE(s+2) -> ds_read/MFMA/|z|/store.
//   - stores share the in-order vmcnt queue (CDNA unified counter): steady
//     count = stores(s-2)[8] + stage(s+1)[4] + stores(s-1)[8] = 20.
//   - W in regs (loaded once, drained before priming so counts stay exact).
// Keeps: slab mapping (r=blockIdx&15), source-pre-swizzled DMA staging.

typedef __attribute__((ext_vector_type(8))) __bf16 bf16x8;
typedef __attribute__((ext_vector_type(4))) float f32x4;

#define R_TOT 16
#define S_TOT 128
#define P_TOT 128
#define RS 2048            // x row stride (floats)
#define RP 2048            // out row stride (floats)
#define ROWS_PER_BLOCK 256
#define STRIP 16
#define NSTRIPS 16

typedef const __attribute__((address_space(1))) void* gas_t;
typedef __attribute__((address_space(3))) void* las_t;

__global__ __launch_bounds__(256, 3) void cproj_kernel(
    const float* __restrict__ x_real,
    const float* __restrict__ x_imag,
    const float* __restrict__ proj,
    float* __restrict__ out)
{
    // ring of 3 strip buffers; rows chunk-swizzled at the GLOBAL source
    // (rule #21): LDS[row][u] (16B units) holds global chunk (u ^ (row&7)).
    __shared__ __attribute__((aligned(16))) float xb[3][2][STRIP][128];

    const int tid  = threadIdx.x;
    const int r    = blockIdx.x & 15;   // co-scheduled blocks span all r
    const int br   = blockIdx.x >> 4;
    const int lane = tid & 63;
    const int wid  = tid >> 6;          // 0..3: owns p-range [32*wid, +32)
    const int m    = lane & 15;
    const int g    = lane >> 4;         // 0..3 k-group / D row group
    const int b_base = br * ROWS_PER_BLOCK;

    // staging split: wave w stages array (w>>1), rows [(w&1)*8, +8): 4 DMA ops
    const int st_arr = wid >> 1;
    const int st_r0  = (wid & 1) * 8;
    const float* xsrc = (st_arr == 0) ? x_real : x_imag;

#define STAGE(strip_)                                                         \
    do {                                                                      \
        _Pragma("unroll")                                                     \
        for (int i = 0; i < 4; ++i) {                                         \
            const int row = st_r0 + 2 * i + (lane >> 5);                      \
            const int gb  = b_base + (strip_) * STRIP + row;                  \
            const float* gp = xsrc + (size_t)gb * RS + r * S_TOT              \
                              + (((lane & 31) ^ (row & 7)) << 2);             \
            __builtin_amdgcn_global_load_lds(                                 \
                (gas_t)gp,                                                    \
                (las_t)&xb[(strip_) % 3][st_arr][st_r0 + 2 * i][0],           \
                16, 0, 0);                                                    \
        }                                                                     \
    } while (0)

    // ---- W into registers (L2-hot, 1MB total), then drain so the manual
    // vmcnt counts below are exact ----
    bf16x8 wf[2][4];  // p = wid*32 + nt*16 + m ; k = kk*32 + g*8 + j
    {
        const float* wrp = proj + (size_t)r * (S_TOT * P_TOT) + wid * 32 + m;
        #pragma unroll
        for (int nt = 0; nt < 2; ++nt) {
            #pragma unroll
            for (int kk = 0; kk < 4; ++kk) {
                bf16x8 w;
                #pragma unroll
                for (int j = 0; j < 8; ++j) {
                    w[j] = (__bf16)wrp[(size_t)(kk * 32 + g * 8 + j) * P_TOT
                                       + nt * 16];
                }
                wf[nt][kk] = w;
            }
        }
    }
    asm volatile("s_waitcnt vmcnt(0)" ::: "memory");

    // ---- prime: stages 0,1 in flight ----
    STAGE(0);
    STAGE(1);

#define ITER(s_, vm_)                                                         \
    {                                                                         \
        asm volatile("s_waitcnt vmcnt(" #vm_ ")" ::: "memory");               \
        __builtin_amdgcn_s_barrier();                                         \
        __builtin_amdgcn_sched_barrier(0);                                    \
        if ((s_) + 2 < NSTRIPS) STAGE((s_) + 2);                              \
        bf16x8 ar[2][4];                                                      \
        _Pragma("unroll")                                                     \
        for (int a = 0; a < 2; ++a) {                                         \
            _Pragma("unroll")                                                 \
            for (int kk = 0; kk < 4; ++kk) {                                  \
                const int c0  = kk * 8 + 2 * g;                               \
                const int s0i = ((c0) ^ (m & 7)) << 2;                        \
                const int s1i = ((c0 + 1) ^ (m & 7)) << 2;                    \
                f32x4 lo = *(const f32x4*)&xb[(s_) % 3][a][m][s0i];           \
                f32x4 hi = *(const f32x4*)&xb[(s_) % 3][a][m][s1i];           \
                bf16x8 t;                                                     \
                _Pragma("unroll")                                             \
                for (int j = 0; j < 4; ++j) {                                 \
                    t[j]     = (__bf16)lo[j];                                 \
                    t[j + 4] = (__bf16)hi[j];                                 \
                }                                                             \
                ar[a][kk] = t;                                                \
            }                                                                 \
        }                                                                     \
        f32x4 acc[2][2]; /* [nt][re/im] */                                    \
        acc[0][0] = (f32x4)0.0f; acc[0][1] = (f32x4)0.0f;                     \
        acc[1][0] = (f32x4)0.0f; acc[1][1] = (f32x4)0.0f;                     \
        _Pragma("unroll")                                                     \
        for (int kk = 0; kk < 4; ++kk) {                                      \
            _Pragma("unroll")                                                 \
            for (int nt = 0; nt < 2; ++nt) {                                  \
                acc[nt][0] = __builtin_amdgcn_mfma_f32_16x16x32_bf16(         \
                    ar[0][kk], wf[nt][kk], acc[nt][0], 0, 0, 0);              \
                acc[nt][1] = __builtin_amdgcn_mfma_f32_16x16x32_bf16(         \
                    ar[1][kk], wf[nt][kk], acc[nt][1], 0, 0, 0);              \
            }                                                                 \
        }                                                                     \
        float* po = out + (size_t)(b_base + (s_) * STRIP + g * 4) * RP        \
                    + r * P_TOT + wid * 32 + m;                               \
        _Pragma("unroll")                                                     \
        for (int nt = 0; nt < 2; ++nt) {                                      \
            _Pragma("unroll")                                                 \
            for (int j = 0; j < 4; ++j) {                                     \
                float re = acc[nt][0][j];                                     \
                float im = acc[nt][1][j];                                     \
                po[(size_t)j * RP + nt * 16] = sqrtf(re * re + im * im);      \
            }                                                                 \
        }                                                                     \
    }

    // wait counts: ops newer than stage(s) at iter s =
    //   s=0: stage1 = 4
    //   s=1: stage2 + stores0 = 12
    //   2<=s<=14: stores(s-2) + stage(s+1) + stores(s-1) = 20
    //   s=15: stores13 + stores14 = 16   (stage16 never issued)
    ITER(0, 4)
    ITER(1, 12)
    ITER(2, 20)
    ITER(3, 20)
    ITER(4, 20)
    ITER(5, 20)
    ITER(6, 20)
    ITER(7, 20)
    ITER(8, 20)
    ITER(9, 20)
    ITER(10, 20)
    ITER(11, 20)
    ITER(12, 20)
    ITER(13, 20)
    ITER(14, 20)
    ITER(15, 16)
#undef ITER
#undef STAGE
}

extern "C" void kernel_launch(void* const* d_in, const int* in_sizes, int n_in,
                              void* d_out, int out_size, void* d_ws, size_t ws_size,
                              hipStream_t stream) {
    const float* x_real = (const float*)d_in[0];
    const float* x_imag = (const float*)d_in[1];
    const float* proj   = (const float*)d_in[2];
    float* out = (float*)d_out;

    dim3 grid(R_TOT * 128);  // 2048 blocks
    dim3 block(256);
    cproj_kernel<<<grid, block, 0, stream>>>(x_real, x_imag, proj, out);
}

// Round 7
// 159.043 us; speedup vs baseline: 1.0331x; 1.0331x over previous
//
#include <hip/hip_runtime.h>
#include <hip/hip_bf16.h>
#include <math.h>

// ComplexProjection: out[b,r,p] = | sum_s complex(xr,xi)[b,r,s] * w[r,s,p] |
// B=32768, R=16, S=128, P=128. Combined-traffic floor ~770MB.
// R7: identical to R6 except block->work decode: XCD-slab affinity.
//   All 16 r-blocks of slab br land on XCD (br&7) (assuming bid%8 XCD
//   round-robin) and are launched consecutively -> each 8KB DRAM page of x
//   is covered densely, in a tight time window, through ONE L2 (slab 2MB
//   fits the XCD's 4MB L2) instead of 16 drifting 512B slices from 8 XCDs.
// R6 base: counted-vmcnt 3-buffer DMA ring, W in regs, source-swizzled DMA.

typedef __attribute__((ext_vector_type(8))) __bf16 bf16x8;
typedef __attribute__((ext_vector_type(4))) float f32x4;

#define R_TOT 16
#define S_TOT 128
#define P_TOT 128
#define RS 2048            // x row stride (floats)
#define RP 2048            // out row stride (floats)
#define ROWS_PER_BLOCK 256
#define STRIP 16
#define NSTRIPS 16

typedef const __attribute__((address_space(1))) void* gas_t;
typedef __attribute__((address_space(3))) void* las_t;

__global__ __launch_bounds__(256, 3) void cproj_kernel(
    const float* __restrict__ x_real,
    const float* __restrict__ x_imag,
    const float* __restrict__ proj,
    float* __restrict__ out)
{
    // ring of 3 strip buffers; rows chunk-swizzled at the GLOBAL source
    // (rule #21): LDS[row][u] (16B units) holds global chunk (u ^ (row&7)).
    __shared__ __attribute__((aligned(16))) float xb[3][2][STRIP][128];

    const int tid  = threadIdx.x;
    const int bid  = blockIdx.x;
    // XCD-slab affinity decode: xcd = bid&7 (round-robin assumption),
    // r = (bid>>3)&15, br = xcd + 8*(bid>>7). 16 consecutive bids on one
    // XCD = the 16 r-blocks of one slab.
    const int r    = (bid >> 3) & 15;
    const int br   = (bid & 7) | ((bid >> 7) << 3);
    const int lane = tid & 63;
    const int wid  = tid >> 6;          // 0..3: owns p-range [32*wid, +32)
    const int m    = lane & 15;
    const int g    = lane >> 4;         // 0..3 k-group / D row group
    const int b_base = br * ROWS_PER_BLOCK;

    // staging split: wave w stages array (w>>1), rows [(w&1)*8, +8): 4 DMA ops
    const int st_arr = wid >> 1;
    const int st_r0  = (wid & 1) * 8;
    const float* xsrc = (st_arr == 0) ? x_real : x_imag;

#define STAGE(strip_)                                                         \
    do {                                                                      \
        _Pragma("unroll")                                                     \
        for (int i = 0; i < 4; ++i) {                                         \
            const int row = st_r0 + 2 * i + (lane >> 5);                      \
            const int gb  = b_base + (strip_) * STRIP + row;                  \
            const float* gp = xsrc + (size_t)gb * RS + r * S_TOT              \
                              + (((lane & 31) ^ (row & 7)) << 2);             \
            __builtin_amdgcn_global_load_lds(                                 \
                (gas_t)gp,                                                    \
                (las_t)&xb[(strip_) % 3][st_arr][st_r0 + 2 * i][0],           \
                16, 0, 0);                                                    \
        }                                                                     \
    } while (0)

    // ---- W into registers (L2-hot, 1MB total), then drain so the manual
    // vmcnt counts below are exact ----
    bf16x8 wf[2][4];  // p = wid*32 + nt*16 + m ; k = kk*32 + g*8 + j
    {
        const float* wrp = proj + (size_t)r * (S_TOT * P_TOT) + wid * 32 + m;
        #pragma unroll
        for (int nt = 0; nt < 2; ++nt) {
            #pragma unroll
            for (int kk = 0; kk < 4; ++kk) {
                bf16x8 w;
                #pragma unroll
                for (int j = 0; j < 8; ++j) {
                    w[j] = (__bf16)wrp[(size_t)(kk * 32 + g * 8 + j) * P_TOT
                                       + nt * 16];
                }
                wf[nt][kk] = w;
            }
        }
    }
    asm volatile("s_waitcnt vmcnt(0)" ::: "memory");

    // ---- prime: stages 0,1 in flight ----
    STAGE(0);
    STAGE(1);

#define ITER(s_, vm_)                                                         \
    {                                                                         \
        asm volatile("s_waitcnt vmcnt(" #vm_ ")" ::: "memory");               \
        __builtin_amdgcn_s_barrier();                                         \
        __builtin_amdgcn_sched_barrier(0);                                    \
        if ((s_) + 2 < NSTRIPS) STAGE((s_) + 2);                              \
        bf16x8 ar[2][4];                                                      \
        _Pragma("unroll")                                                     \
        for (int a = 0; a < 2; ++a) {                                         \
            _Pragma("unroll")                                                 \
            for (int kk = 0; kk < 4; ++kk) {                                  \
                const int c0  = kk * 8 + 2 * g;                               \
                const int s0i = ((c0) ^ (m & 7)) << 2;                        \
                const int s1i = ((c0 + 1) ^ (m & 7)) << 2;                    \
                f32x4 lo = *(const f32x4*)&xb[(s_) % 3][a][m][s0i];           \
                f32x4 hi = *(const f32x4*)&xb[(s_) % 3][a][m][s1i];           \
                bf16x8 t;                                                     \
                _Pragma("unroll")                                             \
                for (int j = 0; j < 4; ++j) {                                 \
                    t[j]     = (__bf16)lo[j];                                 \
                    t[j + 4] = (__bf16)hi[j];                                 \
                }                                                             \
                ar[a][kk] = t;                                                \
            }                                                                 \
        }                                                                     \
        f32x4 acc[2][2]; /* [nt][re/im] */                                    \
        acc[0][0] = (f32x4)0.0f; acc[0][1] = (f32x4)0.0f;                     \
        acc[1][0] = (f32x4)0.0f; acc[1][1] = (f32x4)0.0f;                     \
        _Pragma("unroll")                                                     \
        for (int kk = 0; kk < 4; ++kk) {                                      \
            _Pragma("unroll")                                                 \
            for (int nt = 0; nt < 2; ++nt) {                                  \
                acc[nt][0] = __builtin_amdgcn_mfma_f32_16x16x32_bf16(         \
                    ar[0][kk], wf[nt][kk], acc[nt][0], 0, 0, 0);              \
                acc[nt][1] = __builtin_amdgcn_mfma_f32_16x16x32_bf16(         \
                    ar[1][kk], wf[nt][kk], acc[nt][1], 0, 0, 0);              \
            }                                                                 \
        }                                                                     \
        float* po = out + (size_t)(b_base + (s_) * STRIP + g * 4) * RP        \
                    + r * P_TOT + wid * 32 + m;                               \
        _Pragma("unroll")                                                     \
        for (int nt = 0; nt < 2; ++nt) {                                      \
            _Pragma("unroll")                                                 \
            for (int j = 0; j < 4; ++j) {                                     \
                float re = acc[nt][0][j];                                     \
                float im = acc[nt][1][j];                                     \
                po[(size_t)j * RP + nt * 16] = sqrtf(re * re + im * im);      \
            }                                                                 \
        }                                                                     \
    }

    // wait counts: ops newer than stage(s) at iter s =
    //   s=0: stage1 = 4
    //   s=1: stage2 + stores0 = 12
    //   2<=s<=14: stores(s-2) + stage(s+1) + stores(s-1) = 20
    //   s=15: stores13 + stores14 = 16   (stage16 never issued)
    ITER(0, 4)
    ITER(1, 12)
    ITER(2, 20)
    ITER(3, 20)
    ITER(4, 20)
    ITER(5, 20)
    ITER(6, 20)
    ITER(7, 20)
    ITER(8, 20)
    ITER(9, 20)
    ITER(10, 20)
    ITER(11, 20)
    ITER(12, 20)
    ITER(13, 20)
    ITER(14, 20)
    ITER(15, 16)
#undef ITER
#undef STAGE
}

extern "C" void kernel_launch(void* const* d_in, const int* in_sizes, int n_in,
                              void* d_out, int out_size, void* d_ws, size_t ws_size,
                              hipStream_t stream) {
    const float* x_real = (const float*)d_in[0];
    const float* x_imag = (const float*)d_in[1];
    const float* proj   = (const float*)d_in[2];
    float* out = (float*)d_out;

    dim3 grid(R_TOT * 128);  // 2048 blocks
    dim3 block(256);
    cproj_kernel<<<grid, block, 0, stream>>>(x_real, x_imag, proj, out);
}

// Round 8
// 155.037 us; speedup vs baseline: 1.0598x; 1.0258x over previous
//
#include <hip/hip_runtime.h>
#include <hip/hip_bf16.h>
#include <math.h>

// ComplexProjection: out[b,r,p] = | sum_s complex(xr,xi)[b,r,s] * w[r,s,p] |
// B=32768, R=16, S=128, P=128.
// R8: read-granularity experiment. Each block owns FOUR consecutive r values
// for a 256-row slab, so each staged x row is a 2KB CONTIGUOUS read (R1-R7:
// 512B at 8KB stride -> all pinned at ~3.0-3.4 TB/s; copy bench with multi-KB
// sequential runs hits 6.3). Output rows likewise 2KB contiguous.
//   - 512-thread blocks, 8 waves: wave = (rr = local r, ph = p half).
//   - double-buffered 64KB DMA stages (128KB LDS, 1 block/CU); counted
//     vmcnt(16), never drained in-loop; stage s+1 in flight during compute s.
//   - W in regs (wf[4][4] bf16x8 = 64 VGPR/wave).
//   - low-3-bit XOR chunk swizzle (same involution at DMA source and ds_read,
//     rule #21) -> uniform bank spread for the 16-row ds_read_b128 pattern.

typedef __attribute__((ext_vector_type(8))) __bf16 bf16x8;
typedef __attribute__((ext_vector_type(4))) float f32x4;

#define RS 2048            // x row stride (floats)
#define RP 2048            // out row stride (floats)
#define STRIP 16
#define NSTRIPS 16

typedef const __attribute__((address_space(1))) void* gas_t;
typedef __attribute__((address_space(3))) void* las_t;

__global__ __launch_bounds__(512, 2) void cproj_kernel(
    const float* __restrict__ x_real,
    const float* __restrict__ x_imag,
    const float* __restrict__ proj,
    float* __restrict__ out)
{
    // [buf][arr(re/im)][row][4r x 128 floats]. Row segment = 128 16B-chunks;
    // physical chunk p holds logical chunk p ^ (row&7) (low-3-bit involution).
    __shared__ __attribute__((aligned(16))) float xb[2][2][STRIP][512];

    const int tid  = threadIdx.x;
    const int bid  = blockIdx.x;
    const int r0   = (bid & 3) * 4;        // r-group base
    const int b_base = (bid >> 2) * 256;   // slab base

    const int lane = tid & 63;
    const int wid  = tid >> 6;             // 0..7
    const int rr   = wid >> 1;             // local r (0..3)
    const int ph   = wid & 1;              // p half
    const int p0   = ph * 64;
    const int m    = lane & 15;
    const int g    = lane >> 4;            // k-group / D row group

    // staging role: waves 0-3 stage x_real rows 4w..4w+3, waves 4-7 x_imag
    const int st_arr  = wid >> 2;
    const int st_row0 = (wid & 3) * 4;
    const float* xsrc = st_arr ? x_imag : x_real;

#define STAGE(buf_, strip_)                                                   \
    do {                                                                      \
        _Pragma("unroll")                                                     \
        for (int i = 0; i < 8; ++i) {                                         \
            const int row  = st_row0 + (i >> 1);                              \
            const int half = i & 1;                                           \
            const float* gp = xsrc                                            \
                + (size_t)(b_base + (strip_) * STRIP + row) * RS + r0 * 128   \
                + (((half * 64 + lane) ^ (row & 7)) << 2);                    \
            __builtin_amdgcn_global_load_lds(                                 \
                (gas_t)gp, (las_t)&xb[buf_][st_arr][row][half * 256],         \
                16, 0, 0);                                                    \
        }                                                                     \
    } while (0)

    // ---- prologue: stage strip 0; W into regs; drain once ----
    STAGE(0, 0);

    bf16x8 wf[4][4];  // [nt][kk]: p = p0 + nt*16 + m, k = kk*32 + g*8 + j
    {
        const float* wp = proj + (size_t)(r0 + rr) * (128 * 128) + p0 + m;
        #pragma unroll
        for (int nt = 0; nt < 4; ++nt) {
            #pragma unroll
            for (int kk = 0; kk < 4; ++kk) {
                bf16x8 w;
                #pragma unroll
                for (int j = 0; j < 8; ++j) {
                    w[j] = (__bf16)wp[(size_t)(kk * 32 + g * 8 + j) * 128
                                      + nt * 16];
                }
                wf[nt][kk] = w;
            }
        }
    }
    asm volatile("s_waitcnt vmcnt(0)" ::: "memory");  // stage0 + W complete

#define ITER(s_)                                                              \
    {                                                                         \
        /* queue at wait: [stage(s_) 8, stores(s_-1) 16] -> allow 16 */       \
        asm volatile("s_waitcnt vmcnt(16)" ::: "memory");                     \
        __builtin_amdgcn_s_barrier();                                         \
        __builtin_amdgcn_sched_barrier(0);                                    \
        if ((s_) + 1 < NSTRIPS) STAGE(((s_) + 1) & 1, (s_) + 1);              \
        bf16x8 ar[2][4];                                                      \
        _Pragma("unroll")                                                     \
        for (int a = 0; a < 2; ++a) {                                         \
            _Pragma("unroll")                                                 \
            for (int kk = 0; kk < 4; ++kk) {                                  \
                const int base = rr * 32 + kk * 8;                            \
                const int clo  = base + ((2 * g) ^ (m & 7));                  \
                const int chi  = base + ((2 * g + 1) ^ (m & 7));              \
                f32x4 lo = *(const f32x4*)&xb[(s_) & 1][a][m][clo * 4];       \
                f32x4 hi = *(const f32x4*)&xb[(s_) & 1][a][m][chi * 4];       \
                bf16x8 t;                                                     \
                _Pragma("unroll")                                             \
                for (int j = 0; j < 4; ++j) {                                 \
                    t[j]     = (__bf16)lo[j];                                 \
                    t[j + 4] = (__bf16)hi[j];                                 \
                }                                                             \
                ar[a][kk] = t;                                                \
            }                                                                 \
        }                                                                     \
        f32x4 acc[4][2];                                                      \
        _Pragma("unroll")                                                     \
        for (int nt = 0; nt < 4; ++nt) {                                      \
            acc[nt][0] = (f32x4)0.0f;                                         \
            acc[nt][1] = (f32x4)0.0f;                                         \
        }                                                                     \
        _Pragma("unroll")                                                     \
        for (int kk = 0; kk < 4; ++kk) {                                      \
            _Pragma("unroll")                                                 \
            for (int nt = 0; nt < 4; ++nt) {                                  \
                acc[nt][0] = __builtin_amdgcn_mfma_f32_16x16x32_bf16(         \
                    ar[0][kk], wf[nt][kk], acc[nt][0], 0, 0, 0);              \
                acc[nt][1] = __builtin_amdgcn_mfma_f32_16x16x32_bf16(         \
                    ar[1][kk], wf[nt][kk], acc[nt][1], 0, 0, 0);              \
            }                                                                 \
        }                                                                     \
        /* D mapping (m89): col = lane&15 -> p, row = g*4+j -> b */           \
        float* po = out + (size_t)(b_base + (s_) * STRIP + g * 4) * RP        \
                    + (r0 + rr) * 128 + p0 + m;                               \
        _Pragma("unroll")                                                     \
        for (int nt = 0; nt < 4; ++nt) {                                      \
            _Pragma("unroll")                                                 \
            for (int j = 0; j < 4; ++j) {                                     \
                float re = acc[nt][0][j];                                     \
                float im = acc[nt][1][j];                                     \
                po[(size_t)j * RP + nt * 16] = sqrtf(re * re + im * im);      \
            }                                                                 \
        }                                                                     \
    }

    ITER(0)
    ITER(1)
    ITER(2)
    ITER(3)
    ITER(4)
    ITER(5)
    ITER(6)
    ITER(7)
    ITER(8)
    ITER(9)
    ITER(10)
    ITER(11)
    ITER(12)
    ITER(13)
    ITER(14)
    ITER(15)
#undef ITER
#undef STAGE
}

extern "C" void kernel_launch(void* const* d_in, const int* in_sizes, int n_in,
                              void* d_out, int out_size, void* d_ws, size_t ws_size,
                              hipStream_t stream) {
    const float* x_real = (const float*)d_in[0];
    const float* x_imag = (const float*)d_in[1];
    const float* proj   = (const float*)d_in[2];
    float* out = (float*)d_out;

    dim3 grid(512);    // 128 slabs x 4 r-groups
    dim3 block(512);
    cproj_kernel<<<grid, block, 0, stream>>>(x_real, x_imag, proj, out);
}

// Round 9
// 139.137 us; speedup vs baseline: 1.1809x; 1.1143x over previous
//
#include <hip/hip_runtime.h>
#include <hip/hip_bf16.h>
#include <math.h>

// ComplexProjection: out[b,r,p] = | sum_s complex(xr,xi)[b,r,s] * w[r,s,p] |
// B=32768, R=16, S=128, P=128.
// R9: single-variable A/B vs R8 — NT (non-temporal) cache policy on the x
// stage DMA reads (aux=2 = CPol NT bit on gfx940+/gfx950). x stops
// allocating/hitting L3. Discriminates:
//   (a) IF$-hit path is the ~3.3 TB/s read throttle -> NT helps (dur 120-135)
//   (b) per-direction read-path ceiling -> null -> we are AT the roofline
//       (512 MB reads / 3.3 TB/s = 155 us = current bench).
// R8 base: 4-r-group blocks (2KB contiguous rows), 512 thr, 2x64KB DMA
// double buffer, counted vmcnt(16), W in regs, XOR chunk swizzle.

typedef __attribute__((ext_vector_type(8))) __bf16 bf16x8;
typedef __attribute__((ext_vector_type(4))) float f32x4;

#define RS 2048            // x row stride (floats)
#define RP 2048            // out row stride (floats)
#define STRIP 16
#define NSTRIPS 16

typedef const __attribute__((address_space(1))) void* gas_t;
typedef __attribute__((address_space(3))) void* las_t;

__global__ __launch_bounds__(512, 2) void cproj_kernel(
    const float* __restrict__ x_real,
    const float* __restrict__ x_imag,
    const float* __restrict__ proj,
    float* __restrict__ out)
{
    // [buf][arr(re/im)][row][4r x 128 floats]. Row segment = 128 16B-chunks;
    // physical chunk p holds logical chunk p ^ (row&7) (low-3-bit involution).
    __shared__ __attribute__((aligned(16))) float xb[2][2][STRIP][512];

    const int tid  = threadIdx.x;
    const int bid  = blockIdx.x;
    const int r0   = (bid & 3) * 4;        // r-group base
    const int b_base = (bid >> 2) * 256;   // slab base

    const int lane = tid & 63;
    const int wid  = tid >> 6;             // 0..7
    const int rr   = wid >> 1;             // local r (0..3)
    const int ph   = wid & 1;              // p half
    const int p0   = ph * 64;
    const int m    = lane & 15;
    const int g    = lane >> 4;            // k-group / D row group

    // staging role: waves 0-3 stage x_real rows 4w..4w+3, waves 4-7 x_imag
    const int st_arr  = wid >> 2;
    const int st_row0 = (wid & 3) * 4;
    const float* xsrc = st_arr ? x_imag : x_real;

#define STAGE(buf_, strip_)                                                   \
    do {                                                                      \
        _Pragma("unroll")                                                     \
        for (int i = 0; i < 8; ++i) {                                         \
            const int row  = st_row0 + (i >> 1);                              \
            const int half = i & 1;                                           \
            const float* gp = xsrc                                            \
                + (size_t)(b_base + (strip_) * STRIP + row) * RS + r0 * 128   \
                + (((half * 64 + lane) ^ (row & 7)) << 2);                    \
            __builtin_amdgcn_global_load_lds(                                 \
                (gas_t)gp, (las_t)&xb[buf_][st_arr][row][half * 256],         \
                16, 0, 2 /* CPol NT: stream, don't allocate in L2/IF$ */);    \
        }                                                                     \
    } while (0)

    // ---- prologue: stage strip 0; W into regs; drain once ----
    STAGE(0, 0);

    bf16x8 wf[4][4];  // [nt][kk]: p = p0 + nt*16 + m, k = kk*32 + g*8 + j
    {
        const float* wp = proj + (size_t)(r0 + rr) * (128 * 128) + p0 + m;
        #pragma unroll
        for (int nt = 0; nt < 4; ++nt) {
            #pragma unroll
            for (int kk = 0; kk < 4; ++kk) {
                bf16x8 w;
                #pragma unroll
                for (int j = 0; j < 8; ++j) {
                    w[j] = (__bf16)wp[(size_t)(kk * 32 + g * 8 + j) * 128
                                      + nt * 16];
                }
                wf[nt][kk] = w;
            }
        }
    }
    asm volatile("s_waitcnt vmcnt(0)" ::: "memory");  // stage0 + W complete

#define ITER(s_)                                                              \
    {                                                                         \
        /* queue at wait: [stage(s_) 8, stores(s_-1) 16] -> allow 16 */       \
        asm volatile("s_waitcnt vmcnt(16)" ::: "memory");                     \
        __builtin_amdgcn_s_barrier();                                         \
        __builtin_amdgcn_sched_barrier(0);                                    \
        if ((s_) + 1 < NSTRIPS) STAGE(((s_) + 1) & 1, (s_) + 1);              \
        bf16x8 ar[2][4];                                                      \
        _Pragma("unroll")                                                     \
        for (int a = 0; a < 2; ++a) {                                         \
            _Pragma("unroll")                                                 \
            for (int kk = 0; kk < 4; ++kk) {                                  \
                const int base = rr * 32 + kk * 8;                            \
                const int clo  = base + ((2 * g) ^ (m & 7));                  \
                const int chi  = base + ((2 * g + 1) ^ (m & 7));              \
                f32x4 lo = *(const f32x4*)&xb[(s_) & 1][a][m][clo * 4];       \
                f32x4 hi = *(const f32x4*)&xb[(s_) & 1][a][m][chi * 4];       \
                bf16x8 t;                                                     \
                _Pragma("unroll")                                             \
                for (int j = 0; j < 4; ++j) {                                 \
                    t[j]     = (__bf16)lo[j];                                 \
                    t[j + 4] = (__bf16)hi[j];                                 \
                }                                                             \
                ar[a][kk] = t;                                                \
            }                                                                 \
        }                                                                     \
        f32x4 acc[4][2];                                                      \
        _Pragma("unroll")                                                     \
        for (int nt = 0; nt < 4; ++nt) {                                      \
            acc[nt][0] = (f32x4)0.0f;                                         \
            acc[nt][1] = (f32x4)0.0f;                                         \
        }                                                                     \
        _Pragma("unroll")                                                     \
        for (int kk = 0; kk < 4; ++kk) {                                      \
            _Pragma("unroll")                                                 \
            for (int nt = 0; nt < 4; ++nt) {                                  \
                acc[nt][0] = __builtin_amdgcn_mfma_f32_16x16x32_bf16(         \
                    ar[0][kk], wf[nt][kk], acc[nt][0], 0, 0, 0);              \
                acc[nt][1] = __builtin_amdgcn_mfma_f32_16x16x32_bf16(         \
                    ar[1][kk], wf[nt][kk], acc[nt][1], 0, 0, 0);              \
            }                                                                 \
        }                                                                     \
        /* D mapping (m89): col = lane&15 -> p, row = g*4+j -> b */           \
        float* po = out + (size_t)(b_base + (s_) * STRIP + g * 4) * RP        \
                    + (r0 + rr) * 128 + p0 + m;                               \
        _Pragma("unroll")                                                     \
        for (int nt = 0; nt < 4; ++nt) {                                      \
            _Pragma("unroll")                                                 \
            for (int j = 0; j < 4; ++j) {                                     \
                float re = acc[nt][0][j];                                     \
                float im = acc[nt][1][j];                                     \
                po[(size_t)j * RP + nt * 16] = sqrtf(re * re + im * im);      \
            }                                                                 \
        }                                                                     \
    }

    ITER(0)
    ITER(1)
    ITER(2)
    ITER(3)
    ITER(4)
    ITER(5)
    ITER(6)
    ITER(7)
    ITER(8)
    ITER(9)
    ITER(10)
    ITER(11)
    ITER(12)
    ITER(13)
    ITER(14)
    ITER(15)
#undef ITER
#undef STAGE
}

extern "C" void kernel_launch(void* const* d_in, const int* in_sizes, int n_in,
                              void* d_out, int out_size, void* d_ws, size_t ws_size,
                              hipStream_t stream) {
    const float* x_real = (const float*)d_in[0];
    const float* x_imag = (const float*)d_in[1];
    const float* proj   = (const float*)d_in[2];
    float* out = (float*)d_out;

    dim3 grid(512);    // 128 slabs x 4 r-groups
    dim3 block(512);
    cproj_kernel<<<grid, block, 0, stream>>>(x_real, x_imag, proj, out);
}